// Round 1
// baseline (3244.333 us; speedup 1.0000x reference)
//
#include <hip/hip_runtime.h>

#define B_    64
#define V1_   4096
#define V2_   1024
#define DF_   8
#define K_    25
#define F1_   32
#define F2_   64
#define FC1F_ 512
#define FC2F_ 10
#define E1_   65536
#define E2_   16384
#define C1_   (DF_*B_)   /* 512  */
#define C2_   (F1_*B_)   /* 2048 */
#define FCIN_ 16384

// ---------- input transpose: x[b,v,f] -> X0[v, f*B+b] ----------
__global__ __launch_bounds__(256) void k_transpose_x(const float* __restrict__ x,
                                                     float* __restrict__ X0) {
    int idx = blockIdx.x*256 + threadIdx.x;      // v*512 + f*64 + b
    int b = idx & 63;
    int f = (idx >> 6) & (DF_-1);
    int v = idx >> 9;
    X0[idx] = x[(b*V1_ + v)*DF_ + f];
}

// ---------- CSR build ----------
__global__ __launch_bounds__(256) void k_count(const int* __restrict__ rows, int E,
                                               int* __restrict__ cnt) {
    int e = blockIdx.x*256 + threadIdx.x;
    if (e < E) atomicAdd(&cnt[rows[e]], 1);
}

__global__ __launch_bounds__(256) void k_scan(const int* __restrict__ cnt, int V,
                                              int* __restrict__ offs, int* __restrict__ cursor) {
    __shared__ int psum[256];
    int t = threadIdx.x;
    int chunk = (V + 255) >> 8;            // V is a multiple of 256 here
    int lo = t*chunk;
    int s = 0;
    for (int i = lo; i < lo+chunk; ++i) s += cnt[i];
    psum[t] = s;
    __syncthreads();
    for (int off = 1; off < 256; off <<= 1) {
        int val = (t >= off) ? psum[t-off] : 0;
        __syncthreads();
        psum[t] += val;
        __syncthreads();
    }
    int run = (t == 0) ? 0 : psum[t-1];
    for (int i = lo; i < lo+chunk; ++i) {
        offs[i] = run; cursor[i] = run;
        run += cnt[i];
    }
    if (t == 255) offs[V] = run;
}

__global__ __launch_bounds__(256) void k_scatter(const int* __restrict__ rows,
                                                 const int* __restrict__ cols,
                                                 const float* __restrict__ vals, int E,
                                                 int* __restrict__ cursor,
                                                 int* __restrict__ ecol,
                                                 float* __restrict__ eval) {
    int e = blockIdx.x*256 + threadIdx.x;
    if (e < E) {
        int p = atomicAdd(&cursor[rows[e]], 1);
        ecol[p] = cols[e];
        eval[p] = vals[e];
    }
}

// ---------- fused Chebyshev step + per-k GEMM accumulation ----------
// mode 0: xrow = Xm1 row (k=0, x0), OUT = bias + contribution (init write)
// mode 1: xrow = spmm(Xm1) (k=1), write Xk, OUT += contribution
// mode 2: xrow = 2*spmm(Xm1) - Xm2, write Xk, OUT += contribution
// OUT layout: [V][B][F]
template<int C, int Fin, int F>
__global__ __launch_bounds__(256) void k_cheb_fused(
        int mode, int k,
        const float* __restrict__ Xm1, const float* __restrict__ Xm2,
        float* __restrict__ Xk,
        const int* __restrict__ offs, const int* __restrict__ ecol,
        const float* __restrict__ eval,
        const float* __restrict__ W, const float* __restrict__ bias,
        float* __restrict__ OUT) {
    __shared__ float xrow[C];
    __shared__ float wsh[F*Fin];
    const int v = blockIdx.x;
    const int t = threadIdx.x;

    // stage W[:, fin*K + k] slice: wsh[f*Fin + fin]
    for (int i = t; i < F*Fin; i += 256) {
        int f = i / Fin, fin = i - f*Fin;
        wsh[i] = W[f*(Fin*K_) + fin*K_ + k];
    }

    if (mode == 0) {
        for (int c = t; c < C; c += 256) xrow[c] = Xm1[v*C + c];
    } else if (mode == 1) {
        const int e0 = offs[v], e1 = offs[v+1];
        for (int c = t; c < C; c += 256) {
            float s = 0.f;
            for (int e = e0; e < e1; ++e) s = fmaf(eval[e], Xm1[ecol[e]*C + c], s);
            xrow[c] = s;
            Xk[v*C + c] = s;
        }
    } else {
        const int e0 = offs[v], e1 = offs[v+1];
        for (int c = t; c < C; c += 256) {
            float s = 0.f;
            for (int e = e0; e < e1; ++e) s = fmaf(eval[e], Xm1[ecol[e]*C + c], s);
            float r = 2.f*s - Xm2[v*C + c];
            xrow[c] = r;
            Xk[v*C + c] = r;
        }
    }
    __syncthreads();

    // accumulate: OUT[v][b][f] += sum_fin xrow[fin*64+b] * wsh[f*Fin+fin]
    const int b  = t & 63;
    const int fg = t >> 6;                 // 4 f-groups
    constexpr int FP = F/4;
    float acc[FP];
#pragma unroll
    for (int j = 0; j < FP; ++j) acc[j] = 0.f;
#pragma unroll
    for (int fin = 0; fin < Fin; ++fin) {
        float xv = xrow[fin*64 + b];
#pragma unroll
        for (int j = 0; j < FP; ++j)
            acc[j] = fmaf(xv, wsh[(fg*FP + j)*Fin + fin], acc[j]);
    }
    float* outp = &OUT[(v*64 + b)*F + fg*FP];
    if (mode == 0) {
#pragma unroll
        for (int j = 0; j < FP; ++j) outp[j] = bias[fg*FP + j] + acc[j];
    } else {
#pragma unroll
        for (int j = 0; j < FP; ++j) outp[j] += acc[j];
    }
}

// ---------- relu + 4:1 maxpool, layer1 -> layer2 x0 layout ----------
// X0b[v2, f*64+b] = max(0, max_p OUT1[(4*v2+p)][b][f])
__global__ __launch_bounds__(256) void k_pool1(const float* __restrict__ OUT1,
                                               float* __restrict__ X0b) {
    int idx = blockIdx.x*256 + threadIdx.x;  // v2*2048 + f*64 + b
    int b  = idx & 63;
    int f  = (idx >> 6) & 31;
    int v2 = idx >> 11;
    float m = 0.f;
#pragma unroll
    for (int p = 0; p < 4; ++p)
        m = fmaxf(m, OUT1[((v2*4 + p)*64 + b)*32 + f]);
    X0b[idx] = m;
}

// FCIN[b, v2*64+f] = max(0, max_p OUT2[(4*v2+p)][b][f])
__global__ __launch_bounds__(256) void k_pool2(const float* __restrict__ OUT2,
                                               float* __restrict__ FCIN) {
    int idx = blockIdx.x*256 + threadIdx.x;  // b*16384 + v2*64 + f
    int f  = idx & 63;
    int v2 = (idx >> 6) & 255;
    int b  = idx >> 14;
    float m = 0.f;
#pragma unroll
    for (int p = 0; p < 4; ++p)
        m = fmaxf(m, OUT2[((v2*4 + p)*64 + b)*64 + f]);
    FCIN[idx] = m;
}

// ---------- FC1 ----------
__global__ __launch_bounds__(256) void k_fc1_init(const float* __restrict__ bias,
                                                  float* __restrict__ O) {
    int idx = blockIdx.x*256 + threadIdx.x;  // 64*512
    O[idx] = bias[idx & 511];
}

// grid.x = 8 j-tiles of 64, grid.y = 16 i-chunks of 1024; 4x4 register tile/thread
__global__ __launch_bounds__(256) void k_fc1(const float* __restrict__ A,   // [64][16384]
                                             const float* __restrict__ W,   // [512][16384]
                                             float* __restrict__ O) {       // [64][512]
    __shared__ float At[64][65];
    __shared__ float Wt[64][65];
    const int j0 = blockIdx.x*64;
    const int i0 = blockIdx.y*1024;
    const int t  = threadIdx.x;
    const int tj = (t & 15)*4;
    const int tb = (t >> 4)*4;
    float acc[4][4] = {};
    for (int ic = 0; ic < 1024; ic += 64) {
        for (int l = t; l < 64*64; l += 256) {
            int r = l >> 6, c = l & 63;
            At[r][c] = A[r*FCIN_ + i0 + ic + c];
            Wt[r][c] = W[(j0 + r)*FCIN_ + i0 + ic + c];
        }
        __syncthreads();
#pragma unroll 8
        for (int ii = 0; ii < 64; ++ii) {
            float a0 = At[tb+0][ii], a1 = At[tb+1][ii], a2 = At[tb+2][ii], a3 = At[tb+3][ii];
            float w0 = Wt[tj+0][ii], w1 = Wt[tj+1][ii], w2 = Wt[tj+2][ii], w3 = Wt[tj+3][ii];
            acc[0][0] = fmaf(a0,w0,acc[0][0]); acc[0][1] = fmaf(a0,w1,acc[0][1]);
            acc[0][2] = fmaf(a0,w2,acc[0][2]); acc[0][3] = fmaf(a0,w3,acc[0][3]);
            acc[1][0] = fmaf(a1,w0,acc[1][0]); acc[1][1] = fmaf(a1,w1,acc[1][1]);
            acc[1][2] = fmaf(a1,w2,acc[1][2]); acc[1][3] = fmaf(a1,w3,acc[1][3]);
            acc[2][0] = fmaf(a2,w0,acc[2][0]); acc[2][1] = fmaf(a2,w1,acc[2][1]);
            acc[2][2] = fmaf(a2,w2,acc[2][2]); acc[2][3] = fmaf(a2,w3,acc[2][3]);
            acc[3][0] = fmaf(a3,w0,acc[3][0]); acc[3][1] = fmaf(a3,w1,acc[3][1]);
            acc[3][2] = fmaf(a3,w2,acc[3][2]); acc[3][3] = fmaf(a3,w3,acc[3][3]);
        }
        __syncthreads();
    }
#pragma unroll
    for (int bi = 0; bi < 4; ++bi)
#pragma unroll
        for (int ji = 0; ji < 4; ++ji)
            atomicAdd(&O[(tb+bi)*512 + j0 + tj + ji], acc[bi][ji]);
}

// ---------- FC2 (relu applied to FC1 output here) ----------
__global__ void k_fc2(const float* __restrict__ O1, const float* __restrict__ W2,
                      const float* __restrict__ b2, float* __restrict__ out) {
    int c = blockIdx.x;     // 10
    int b = threadIdx.x;    // 64
    float s = b2[c];
    for (int j = 0; j < 512; ++j)
        s = fmaf(fmaxf(O1[b*512 + j], 0.f), W2[c*512 + j], s);
    out[b*10 + c] = s;
}

extern "C" void kernel_launch(void* const* d_in, const int* in_sizes, int n_in,
                              void* d_out, int out_size, void* d_ws, size_t ws_size,
                              hipStream_t stream) {
    const float* x   = (const float*)d_in[0];
    const int*   l1r = (const int*)d_in[1];
    const int*   l1c = (const int*)d_in[2];
    const float* l1v = (const float*)d_in[3];
    const int*   l2r = (const int*)d_in[4];
    const int*   l2c = (const int*)d_in[5];
    const float* l2v = (const float*)d_in[6];
    const float* w1  = (const float*)d_in[7];
    const float* b1  = (const float*)d_in[8];
    const float* w2  = (const float*)d_in[9];
    const float* b2  = (const float*)d_in[10];
    const float* fw1 = (const float*)d_in[11];
    const float* fb1 = (const float*)d_in[12];
    const float* fw2 = (const float*)d_in[13];
    const float* fb2 = (const float*)d_in[14];
    float* out = (float*)d_out;

    char* wsp = (char*)d_ws;
    size_t off = 0;
    auto alloc = [&](size_t bytes) -> void* {
        void* p = wsp + off;
        off += (bytes + 255) & ~size_t(255);
        return p;
    };
    float* P0   = (float*)alloc((size_t)V1_*C1_*4);
    float* P1   = (float*)alloc((size_t)V1_*C1_*4);
    float* P2   = (float*)alloc((size_t)V1_*C1_*4);
    float* OUT1 = (float*)alloc((size_t)V1_*B_*F1_*4);
    float* OUT2 = (float*)alloc((size_t)V2_*B_*F2_*4);
    float* FCIN = (float*)alloc((size_t)B_*FCIN_*4);
    float* FC1O = (float*)alloc((size_t)B_*FC1F_*4);
    int*   cnt1  = (int*)alloc(V1_*4);
    int*   offs1 = (int*)alloc((V1_+1)*4);
    int*   cur1  = (int*)alloc(V1_*4);
    int*   ecol1 = (int*)alloc((size_t)E1_*4);
    float* eval1 = (float*)alloc((size_t)E1_*4);
    int*   cnt2  = (int*)alloc(V2_*4);
    int*   offs2 = (int*)alloc((V2_+1)*4);
    int*   cur2  = (int*)alloc(V2_*4);
    int*   ecol2 = (int*)alloc((size_t)E2_*4);
    float* eval2 = (float*)alloc((size_t)E2_*4);

    float* P[3] = {P0, P1, P2};

    // --- layer 1 ---
    hipLaunchKernelGGL(k_transpose_x, dim3(V1_*C1_/256), dim3(256), 0, stream, x, P0);
    hipMemsetAsync(cnt1, 0, V1_*4, stream);
    hipLaunchKernelGGL(k_count,   dim3(E1_/256), dim3(256), 0, stream, l1r, E1_, cnt1);
    hipLaunchKernelGGL(k_scan,    dim3(1),       dim3(256), 0, stream, cnt1, V1_, offs1, cur1);
    hipLaunchKernelGGL(k_scatter, dim3(E1_/256), dim3(256), 0, stream, l1r, l1c, l1v, E1_, cur1, ecol1, eval1);

    hipLaunchKernelGGL((k_cheb_fused<C1_,DF_,F1_>), dim3(V1_), dim3(256), 0, stream,
                       0, 0, P0, (const float*)nullptr, (float*)nullptr,
                       offs1, ecol1, eval1, w1, b1, OUT1);
    hipLaunchKernelGGL((k_cheb_fused<C1_,DF_,F1_>), dim3(V1_), dim3(256), 0, stream,
                       1, 1, P0, (const float*)nullptr, P1,
                       offs1, ecol1, eval1, w1, b1, OUT1);
    for (int k = 2; k < K_; ++k) {
        float* xk  = P[k % 3];
        float* xm1 = P[(k+2) % 3];
        float* xm2 = P[(k+1) % 3];
        hipLaunchKernelGGL((k_cheb_fused<C1_,DF_,F1_>), dim3(V1_), dim3(256), 0, stream,
                           2, k, xm1, xm2, xk, offs1, ecol1, eval1, w1, b1, OUT1);
    }
    hipLaunchKernelGGL(k_pool1, dim3(V2_*C2_/256), dim3(256), 0, stream, OUT1, P0);

    // --- layer 2 ---
    hipMemsetAsync(cnt2, 0, V2_*4, stream);
    hipLaunchKernelGGL(k_count,   dim3(E2_/256), dim3(256), 0, stream, l2r, E2_, cnt2);
    hipLaunchKernelGGL(k_scan,    dim3(1),       dim3(256), 0, stream, cnt2, V2_, offs2, cur2);
    hipLaunchKernelGGL(k_scatter, dim3(E2_/256), dim3(256), 0, stream, l2r, l2c, l2v, E2_, cur2, ecol2, eval2);

    hipLaunchKernelGGL((k_cheb_fused<C2_,F1_,F2_>), dim3(V2_), dim3(256), 0, stream,
                       0, 0, P0, (const float*)nullptr, (float*)nullptr,
                       offs2, ecol2, eval2, w2, b2, OUT2);
    hipLaunchKernelGGL((k_cheb_fused<C2_,F1_,F2_>), dim3(V2_), dim3(256), 0, stream,
                       1, 1, P0, (const float*)nullptr, P1,
                       offs2, ecol2, eval2, w2, b2, OUT2);
    for (int k = 2; k < K_; ++k) {
        float* xk  = P[k % 3];
        float* xm1 = P[(k+2) % 3];
        float* xm2 = P[(k+1) % 3];
        hipLaunchKernelGGL((k_cheb_fused<C2_,F1_,F2_>), dim3(V2_), dim3(256), 0, stream,
                           2, k, xm1, xm2, xk, offs2, ecol2, eval2, w2, b2, OUT2);
    }
    hipLaunchKernelGGL(k_pool2, dim3(B_*FCIN_/256), dim3(256), 0, stream, OUT2, FCIN);

    // --- FC ---
    hipLaunchKernelGGL(k_fc1_init, dim3(B_*FC1F_/256), dim3(256), 0, stream, fb1, FC1O);
    hipLaunchKernelGGL(k_fc1, dim3(8, 16), dim3(256), 0, stream, FCIN, fw1, FC1O);
    hipLaunchKernelGGL(k_fc2, dim3(FC2F_), dim3(B_), 0, stream, FC1O, fw2, fb2, out);
}

// Round 2
// 1373.257 us; speedup vs baseline: 2.3625x; 2.3625x over previous
//
#include <hip/hip_runtime.h>
#include <hip/hip_fp16.h>

#define B_    64
#define V1_   4096
#define V2_   1024
#define DF_   8
#define K_    25
#define KP_   32
#define F1_   32
#define F2_   64
#define FC1F_ 512
#define FC2F_ 10
#define E1_   65536
#define E2_   16384
#define C1_   512
#define C2_   2048
#define FCIN_ 16384

__device__ __forceinline__ unsigned short f2bf(float x) {
    unsigned u = __float_as_uint(x);
    u += 0x7FFFu + ((u >> 16) & 1u);
    return (unsigned short)(u >> 16);
}
__device__ __forceinline__ float bf2f(unsigned short h) {
    return __uint_as_float(((unsigned)h) << 16);
}

// ---------- input transpose: x[b,v,fin] -> X0T[(fin*64+b)][v] ----------
__global__ __launch_bounds__(256) void k_transpose_x(const float* __restrict__ x,
                                                     float* __restrict__ X0T) {
    __shared__ float tsh[DF_][B_][16];
    const int t = threadIdx.x;
    const int v0 = blockIdx.x * 16;
    for (int rep = 0; rep < 4; ++rep) {
        int idx = rep*256 + t;            // 1024 (b,vv) pairs
        int b = idx >> 4, vv = idx & 15;
        const float4* p = (const float4*)&x[((size_t)b*V1_ + v0 + vv)*DF_];
        float4 a0 = p[0], a1 = p[1];
        tsh[0][b][vv]=a0.x; tsh[1][b][vv]=a0.y; tsh[2][b][vv]=a0.z; tsh[3][b][vv]=a0.w;
        tsh[4][b][vv]=a1.x; tsh[5][b][vv]=a1.y; tsh[6][b][vv]=a1.z; tsh[7][b][vv]=a1.w;
    }
    __syncthreads();
    for (int rep = 0; rep < 32; ++rep) {
        int idx = rep*256 + t;            // 8192
        int vv = idx & 15, b = (idx >> 4) & 63, fin = idx >> 10;
        X0T[(size_t)(fin*64 + b)*V1_ + v0 + vv] = tsh[fin][b][vv];
    }
}

// ---------- CSR build (padded to 4-edge alignment, packed edges) ----------
__global__ __launch_bounds__(256) void k_count(const int* __restrict__ rows, int E,
                                               int* __restrict__ cnt) {
    int e = blockIdx.x*256 + threadIdx.x;
    if (e < E) atomicAdd(&cnt[rows[e]], 1);
}

__global__ __launch_bounds__(256) void k_scan(const int* __restrict__ cnt, int V,
                                              int* __restrict__ offs, int* __restrict__ cursor) {
    __shared__ int psum[256];
    int t = threadIdx.x;
    int chunk = V >> 8;
    int lo = t*chunk;
    int s = 0;
    for (int i = lo; i < lo+chunk; ++i) s += (cnt[i] + 3) & ~3;
    psum[t] = s;
    __syncthreads();
    for (int off = 1; off < 256; off <<= 1) {
        int val = (t >= off) ? psum[t-off] : 0;
        __syncthreads();
        psum[t] += val;
        __syncthreads();
    }
    int run = (t == 0) ? 0 : psum[t-1];
    for (int i = lo; i < lo+chunk; ++i) {
        offs[i] = run; cursor[i] = run;
        run += (cnt[i] + 3) & ~3;
    }
    if (t == 255) offs[V] = run;
}

__global__ __launch_bounds__(256) void k_scatter(const int* __restrict__ rows,
                                                 const int* __restrict__ cols,
                                                 const float* __restrict__ vals, int E,
                                                 int* __restrict__ cursor,
                                                 unsigned* __restrict__ ep) {
    int e = blockIdx.x*256 + threadIdx.x;
    if (e < E) {
        int p = atomicAdd(&cursor[rows[e]], 1);
        unsigned hv = (unsigned)__half_as_ushort(__float2half(vals[e]));
        ep[p] = (hv << 16) | (unsigned)cols[e];
    }
}

// ---------- persistent Chebyshev recursion (2 columns/block, LDS ping-pong) ----------
// stack layout: [c][w(0..3)][v][kk(0..7)] bf16, i.e. idx = (c*KP + w*8)*V + v*8 + kk
template<int V, int THREADS>
__global__ __launch_bounds__(THREADS) void k_cheb(
        const float* __restrict__ X0T,
        const int* __restrict__ offs, const unsigned* __restrict__ ep,
        unsigned short* __restrict__ stack) {
    constexpr int RPT = V / THREADS;
    __shared__ float bufA[V*2];
    __shared__ float bufB[V*2];
    const int c0 = blockIdx.x * 2;
    const int t = threadIdx.x;
    int e0r[RPT], e1r[RPT];
    float frag[RPT][2][8];

    // k = 0
#pragma unroll
    for (int r = 0; r < RPT; ++r) {
        int v = r*THREADS + t;
        e0r[r] = offs[v]; e1r[r] = offs[v+1];
        float x0 = X0T[(size_t)c0*V + v];
        float x1 = X0T[(size_t)(c0+1)*V + v];
        bufA[v*2]   = x0; frag[r][0][0] = x0;
        bufA[v*2+1] = x1; frag[r][1][0] = x1;
    }
    __syncthreads();

    for (int w = 0; w < 4; ++w) {
#pragma unroll
        for (int kk = 0; kk < 8; ++kk) {
            if (w == 0 && kk == 0) continue;   // k=0 done above
            if (w == 3 && kk >= 1) break;      // k stops at 24
            const float* __restrict__ src = (kk & 1) ? bufA : bufB;
            float* __restrict__ dst       = (kk & 1) ? bufB : bufA;
#pragma unroll
            for (int r = 0; r < RPT; ++r) {
                int v = r*THREADS + t;
                float a00=0,a01=0,a10=0,a11=0,a20=0,a21=0,a30=0,a31=0;
                int e1 = e1r[r];
                for (int e = e0r[r]; e < e1; e += 4) {
                    const uint4 u = *(const uint4*)&ep[e];
                    float w0=__half2float(__ushort_as_half((unsigned short)(u.x>>16)));
                    float w1=__half2float(__ushort_as_half((unsigned short)(u.y>>16)));
                    float w2=__half2float(__ushort_as_half((unsigned short)(u.z>>16)));
                    float w3=__half2float(__ushort_as_half((unsigned short)(u.w>>16)));
                    const float2 g0 = *(const float2*)&src[(u.x&0xFFFFu)*2];
                    const float2 g1 = *(const float2*)&src[(u.y&0xFFFFu)*2];
                    const float2 g2 = *(const float2*)&src[(u.z&0xFFFFu)*2];
                    const float2 g3 = *(const float2*)&src[(u.w&0xFFFFu)*2];
                    a00 = fmaf(w0, g0.x, a00); a01 = fmaf(w0, g0.y, a01);
                    a10 = fmaf(w1, g1.x, a10); a11 = fmaf(w1, g1.y, a11);
                    a20 = fmaf(w2, g2.x, a20); a21 = fmaf(w2, g2.y, a21);
                    a30 = fmaf(w3, g3.x, a30); a31 = fmaf(w3, g3.y, a31);
                }
                float s0 = (a00+a10)+(a20+a30);
                float s1 = (a01+a11)+(a21+a31);
                float x0n, x1n;
                if (w == 0 && kk == 1) { x0n = s0; x1n = s1; }
                else { x0n = 2.f*s0 - dst[v*2]; x1n = 2.f*s1 - dst[v*2+1]; }
                dst[v*2]   = x0n;  frag[r][0][kk] = x0n;
                dst[v*2+1] = x1n;  frag[r][1][kk] = x1n;
            }
            __syncthreads();
        }
        // flush window w (k = w*8 .. w*8+7; w=3 has only kk=0 valid, rest killed by W zero-pad)
#pragma unroll
        for (int r = 0; r < RPT; ++r) {
            int v = r*THREADS + t;
#pragma unroll
            for (int j = 0; j < 2; ++j) {
                uint4 pk;
                pk.x = (unsigned)f2bf(frag[r][j][0]) | ((unsigned)f2bf(frag[r][j][1]) << 16);
                pk.y = (unsigned)f2bf(frag[r][j][2]) | ((unsigned)f2bf(frag[r][j][3]) << 16);
                pk.z = (unsigned)f2bf(frag[r][j][4]) | ((unsigned)f2bf(frag[r][j][5]) << 16);
                pk.w = (unsigned)f2bf(frag[r][j][6]) | ((unsigned)f2bf(frag[r][j][7]) << 16);
                *(uint4*)&stack[((size_t)(c0+j)*KP_ + w*8)*V + (size_t)v*8] = pk;
            }
        }
    }
}

// ---------- conv GEMM: out[v][b][f] = bias + sum_{fin,k} stack[c][k][v]*W[f][fin*K+k]
// fused relu + pool4 epilogue. EPI=1 -> X0T2[(f*64+b)][v2]; EPI=2 -> FCIN_T[(v2*64+f)][b]
template<int V, int FIN, int F, int VT, int THREADS, int EPI>
__global__ __launch_bounds__(THREADS) void k_gemm(
        const unsigned short* __restrict__ stack,
        const float* __restrict__ W, const float* __restrict__ bias,
        float* __restrict__ outp) {
    constexpr int FG  = THREADS / 64;
    constexpr int FPT = F / FG;
    constexpr int TS  = VT*8 + 1;
    __shared__ float Wsh[KP_][F];
    __shared__ float Tsh[64 * TS];
    const int t  = threadIdx.x;
    const int v0 = blockIdx.x * VT;
    const int b  = t & 63;
    const int fg = t >> 6;
    float acc[VT][FPT];
#pragma unroll
    for (int vv = 0; vv < VT; ++vv)
#pragma unroll
        for (int j = 0; j < FPT; ++j) acc[vv][j] = 0.f;

    for (int fin = 0; fin < FIN; ++fin) {
        __syncthreads();
        for (int i = t; i < F*KP_; i += THREADS) {
            int kk = i / F, f = i % F;
            Wsh[kk][f] = (kk < K_) ? W[f*(FIN*K_) + fin*K_ + kk] : 0.f;
        }
        for (int w = 0; w < 4; ++w) {
            __syncthreads();
            for (int idx = t; idx < 64*VT; idx += THREADS) {
                int vv = idx & (VT-1);
                int bb = idx / VT;
                const uint4 raw = *(const uint4*)&stack[((size_t)(fin*64+bb)*KP_ + w*8)*V + (size_t)(v0+vv)*8];
                float* dstp = &Tsh[bb*TS + vv*8];
                dstp[0] = bf2f((unsigned short)(raw.x & 0xFFFFu));
                dstp[1] = bf2f((unsigned short)(raw.x >> 16));
                dstp[2] = bf2f((unsigned short)(raw.y & 0xFFFFu));
                dstp[3] = bf2f((unsigned short)(raw.y >> 16));
                dstp[4] = bf2f((unsigned short)(raw.z & 0xFFFFu));
                dstp[5] = bf2f((unsigned short)(raw.z >> 16));
                dstp[6] = bf2f((unsigned short)(raw.w & 0xFFFFu));
                dstp[7] = bf2f((unsigned short)(raw.w >> 16));
            }
            __syncthreads();
#pragma unroll
            for (int kk = 0; kk < 8; ++kk) {
                float wreg[FPT];
#pragma unroll
                for (int j = 0; j < FPT; j += 4) {
                    float4 wv = *(const float4*)&Wsh[w*8+kk][fg*FPT + j];
                    wreg[j]=wv.x; wreg[j+1]=wv.y; wreg[j+2]=wv.z; wreg[j+3]=wv.w;
                }
#pragma unroll
                for (int vv = 0; vv < VT; ++vv) {
                    float xv = Tsh[b*TS + vv*8 + kk];
#pragma unroll
                    for (int j = 0; j < FPT; ++j)
                        acc[vv][j] = fmaf(xv, wreg[j], acc[vv][j]);
                }
            }
        }
    }

    float bv[FPT];
#pragma unroll
    for (int j = 0; j < FPT; ++j) bv[j] = bias[fg*FPT + j];

    if (EPI == 1) {
#pragma unroll
        for (int g = 0; g < VT/4; ++g) {
            int v2 = (v0 >> 2) + g;
#pragma unroll
            for (int j = 0; j < FPT; ++j) {
                float m = 0.f;
#pragma unroll
                for (int p = 0; p < 4; ++p) m = fmaxf(m, acc[g*4+p][j] + bv[j]);
                outp[((size_t)(fg*FPT + j)*64 + b)*V2_ + v2] = m;
            }
        }
    } else {
        int v2 = v0 >> 2;   // VT == 4
#pragma unroll
        for (int j = 0; j < FPT; ++j) {
            float m = 0.f;
#pragma unroll
            for (int p = 0; p < 4; ++p) m = fmaxf(m, acc[p][j] + bv[j]);
            outp[((size_t)v2*64 + fg*FPT + j)*64 + b] = m;
        }
    }
}

// ---------- FC1: O[b][j] (+= atomics over i-splits), AT layout [i][b] ----------
__global__ __launch_bounds__(256) void k_fc1_init(const float* __restrict__ bias,
                                                  float* __restrict__ O) {
    int idx = blockIdx.x*256 + threadIdx.x;
    O[idx] = bias[idx & (FC1F_-1)];
}

__global__ __launch_bounds__(256) void k_fc1(const float* __restrict__ AT,
                                             const float* __restrict__ W,
                                             float* __restrict__ O) {
    const int t = threadIdx.x;
    const int b = t & 63;
    const int jq = __builtin_amdgcn_readfirstlane(t >> 6);
    const int j0 = blockIdx.x*32 + jq*8;
    const int i0 = blockIdx.y*1024;
    float acc[8] = {};
    for (int i = i0; i < i0 + 1024; i += 4) {
        float a0 = AT[(size_t)(i+0)*64 + b];
        float a1 = AT[(size_t)(i+1)*64 + b];
        float a2 = AT[(size_t)(i+2)*64 + b];
        float a3 = AT[(size_t)(i+3)*64 + b];
#pragma unroll
        for (int jj = 0; jj < 8; ++jj) {
            const float* wp = &W[(size_t)(j0+jj)*FCIN_ + i];
            acc[jj] = fmaf(a0, wp[0], acc[jj]);
            acc[jj] = fmaf(a1, wp[1], acc[jj]);
            acc[jj] = fmaf(a2, wp[2], acc[jj]);
            acc[jj] = fmaf(a3, wp[3], acc[jj]);
        }
    }
#pragma unroll
    for (int jj = 0; jj < 8; ++jj)
        atomicAdd(&O[b*FC1F_ + j0 + jj], acc[jj]);
}

// ---------- FC2 (relu on FC1 output applied here) ----------
__global__ void k_fc2(const float* __restrict__ O1, const float* __restrict__ W2,
                      const float* __restrict__ b2, float* __restrict__ out) {
    int c = blockIdx.x;     // 10
    int b = threadIdx.x;    // 64
    float s = b2[c];
    for (int j = 0; j < FC1F_; ++j)
        s = fmaf(fmaxf(O1[b*FC1F_ + j], 0.f), W2[c*FC1F_ + j], s);
    out[b*FC2F_ + c] = s;
}

extern "C" void kernel_launch(void* const* d_in, const int* in_sizes, int n_in,
                              void* d_out, int out_size, void* d_ws, size_t ws_size,
                              hipStream_t stream) {
    const float* x   = (const float*)d_in[0];
    const int*   l1r = (const int*)d_in[1];
    const int*   l1c = (const int*)d_in[2];
    const float* l1v = (const float*)d_in[3];
    const int*   l2r = (const int*)d_in[4];
    const int*   l2c = (const int*)d_in[5];
    const float* l2v = (const float*)d_in[6];
    const float* w1  = (const float*)d_in[7];
    const float* b1  = (const float*)d_in[8];
    const float* w2  = (const float*)d_in[9];
    const float* b2  = (const float*)d_in[10];
    const float* fw1 = (const float*)d_in[11];
    const float* fb1 = (const float*)d_in[12];
    const float* fw2 = (const float*)d_in[13];
    const float* fb2 = (const float*)d_in[14];
    float* out = (float*)d_out;

    char* wsp = (char*)d_ws;
    size_t off = 0;
    auto alloc = [&](size_t bytes) -> void* {
        void* p = wsp + off;
        off += (bytes + 255) & ~size_t(255);
        return p;
    };
    float*          X0T1  = (float*)alloc((size_t)C1_*V1_*4);
    unsigned short* STACK = (unsigned short*)alloc((size_t)C1_*V1_*KP_*2);  // shared by both layers
    float*          X0T2  = (float*)alloc((size_t)C2_*V2_*4);
    float*          FCINT = (float*)alloc((size_t)FCIN_*B_*4);
    float*          FC1O  = (float*)alloc((size_t)B_*FC1F_*4);
    int*      cnt1  = (int*)alloc(V1_*4);
    int*      offs1 = (int*)alloc((V1_+1)*4);
    int*      cur1  = (int*)alloc(V1_*4);
    unsigned* ep1   = (unsigned*)alloc((size_t)(E1_ + 4*V1_)*4);
    int*      cnt2  = (int*)alloc(V2_*4);
    int*      offs2 = (int*)alloc((V2_+1)*4);
    int*      cur2  = (int*)alloc(V2_*4);
    unsigned* ep2   = (unsigned*)alloc((size_t)(E2_ + 4*V2_)*4);

    // --- CSR build both layers ---
    hipMemsetAsync(cnt1, 0, V1_*4, stream);
    hipMemsetAsync(ep1, 0, (size_t)(E1_ + 4*V1_)*4, stream);
    hipMemsetAsync(cnt2, 0, V2_*4, stream);
    hipMemsetAsync(ep2, 0, (size_t)(E2_ + 4*V2_)*4, stream);
    hipLaunchKernelGGL(k_count,   dim3(E1_/256), dim3(256), 0, stream, l1r, E1_, cnt1);
    hipLaunchKernelGGL(k_scan,    dim3(1),       dim3(256), 0, stream, cnt1, V1_, offs1, cur1);
    hipLaunchKernelGGL(k_scatter, dim3(E1_/256), dim3(256), 0, stream, l1r, l1c, l1v, E1_, cur1, ep1);
    hipLaunchKernelGGL(k_count,   dim3(E2_/256), dim3(256), 0, stream, l2r, E2_, cnt2);
    hipLaunchKernelGGL(k_scan,    dim3(1),       dim3(256), 0, stream, cnt2, V2_, offs2, cur2);
    hipLaunchKernelGGL(k_scatter, dim3(E2_/256), dim3(256), 0, stream, l2r, l2c, l2v, E2_, cur2, ep2);

    // --- layer 1 ---
    hipLaunchKernelGGL(k_transpose_x, dim3(V1_/16), dim3(256), 0, stream, x, X0T1);
    hipLaunchKernelGGL((k_cheb<V1_,1024>), dim3(C1_/2), dim3(1024), 0, stream,
                       X0T1, offs1, ep1, STACK);
    hipLaunchKernelGGL((k_gemm<V1_,DF_,F1_,8,256,1>), dim3(V1_/8), dim3(256), 0, stream,
                       STACK, w1, b1, X0T2);

    // --- layer 2 ---
    hipLaunchKernelGGL((k_cheb<V2_,256>), dim3(C2_/2), dim3(256), 0, stream,
                       X0T2, offs2, ep2, STACK);
    hipLaunchKernelGGL((k_gemm<V2_,F1_,F2_,4,512,2>), dim3(V2_/4), dim3(512), 0, stream,
                       STACK, w2, b2, FCINT);

    // --- FC ---
    hipLaunchKernelGGL(k_fc1_init, dim3(B_*FC1F_/256), dim3(256), 0, stream, fb1, FC1O);
    hipLaunchKernelGGL(k_fc1, dim3(16, 16), dim3(256), 0, stream, FCINT, fw1, FC1O);
    hipLaunchKernelGGL(k_fc2, dim3(FC2F_), dim3(B_), 0, stream, FC1O, fw2, fb2, out);
}

// Round 3
// 734.257 us; speedup vs baseline: 4.4185x; 1.8703x over previous
//
#include <hip/hip_runtime.h>
#include <hip/hip_fp16.h>

#define B_    64
#define V1_   4096
#define V2_   1024
#define DF_   8
#define K_    25
#define KP_   32
#define F1_   32
#define F2_   64
#define FC1F_ 512
#define FC2F_ 10
#define E1_   65536
#define E2_   16384
#define C1_   512
#define C2_   2048
#define FCIN_ 16384

typedef short bf16x8 __attribute__((ext_vector_type(8)));
typedef float f32x4  __attribute__((ext_vector_type(4)));

__device__ __forceinline__ unsigned short f2bf(float x) {
    unsigned u = __float_as_uint(x);
    u += 0x7FFFu + ((u >> 16) & 1u);
    return (unsigned short)(u >> 16);
}

// ---------- input transpose: x[b,v,fin] -> X0T[(fin*64+b)][v] ----------
__global__ __launch_bounds__(256) void k_transpose_x(const float* __restrict__ x,
                                                     float* __restrict__ X0T) {
    __shared__ float tsh[DF_][B_][16];
    const int t = threadIdx.x;
    const int v0 = blockIdx.x * 16;
    for (int rep = 0; rep < 4; ++rep) {
        int idx = rep*256 + t;
        int b = idx >> 4, vv = idx & 15;
        const float4* p = (const float4*)&x[((size_t)b*V1_ + v0 + vv)*DF_];
        float4 a0 = p[0], a1 = p[1];
        tsh[0][b][vv]=a0.x; tsh[1][b][vv]=a0.y; tsh[2][b][vv]=a0.z; tsh[3][b][vv]=a0.w;
        tsh[4][b][vv]=a1.x; tsh[5][b][vv]=a1.y; tsh[6][b][vv]=a1.z; tsh[7][b][vv]=a1.w;
    }
    __syncthreads();
    for (int rep = 0; rep < 32; ++rep) {
        int idx = rep*256 + t;
        int vv = idx & 15, b = (idx >> 4) & 63, fin = idx >> 10;
        X0T[(size_t)(fin*64 + b)*V1_ + v0 + vv] = tsh[fin][b][vv];
    }
}

// ---------- CSR build (padded to 4-edge alignment, packed edges) ----------
__global__ __launch_bounds__(256) void k_count(const int* __restrict__ rows, int E,
                                               int* __restrict__ cnt) {
    int e = blockIdx.x*256 + threadIdx.x;
    if (e < E) atomicAdd(&cnt[rows[e]], 1);
}

__global__ __launch_bounds__(256) void k_scan(const int* __restrict__ cnt, int V,
                                              int* __restrict__ offs, int* __restrict__ cursor) {
    __shared__ int psum[256];
    int t = threadIdx.x;
    int chunk = V >> 8;
    int lo = t*chunk;
    int s = 0;
    for (int i = lo; i < lo+chunk; ++i) s += (cnt[i] + 3) & ~3;
    psum[t] = s;
    __syncthreads();
    for (int off = 1; off < 256; off <<= 1) {
        int val = (t >= off) ? psum[t-off] : 0;
        __syncthreads();
        psum[t] += val;
        __syncthreads();
    }
    int run = (t == 0) ? 0 : psum[t-1];
    for (int i = lo; i < lo+chunk; ++i) {
        offs[i] = run; cursor[i] = run;
        run += (cnt[i] + 3) & ~3;
    }
    if (t == 255) offs[V] = run;
}

__global__ __launch_bounds__(256) void k_scatter(const int* __restrict__ rows,
                                                 const int* __restrict__ cols,
                                                 const float* __restrict__ vals, int E,
                                                 int* __restrict__ cursor,
                                                 unsigned* __restrict__ ep) {
    int e = blockIdx.x*256 + threadIdx.x;
    if (e < E) {
        int p = atomicAdd(&cursor[rows[e]], 1);
        unsigned hv = (unsigned)__half_as_ushort(__float2half(vals[e]));
        ep[p] = (hv << 16) | (unsigned)cols[e];
    }
}

// ---------- persistent Chebyshev recursion (2 columns/block, LDS ping-pong) ----------
// stack layout: [c][w(0..3)][v][kk(0..7)] bf16
template<int V, int THREADS>
__global__ __launch_bounds__(THREADS) void k_cheb(
        const float* __restrict__ X0T,
        const int* __restrict__ offs, const unsigned* __restrict__ ep,
        unsigned short* __restrict__ stack) {
    constexpr int RPT = V / THREADS;
    __shared__ float bufA[V*2];
    __shared__ float bufB[V*2];
    const int c0 = blockIdx.x * 2;
    const int t = threadIdx.x;
    int e0r[RPT], e1r[RPT];
    float frag[RPT][2][8];

#pragma unroll
    for (int r = 0; r < RPT; ++r) {
        int v = r*THREADS + t;
        e0r[r] = offs[v]; e1r[r] = offs[v+1];
        float x0 = X0T[(size_t)c0*V + v];
        float x1 = X0T[(size_t)(c0+1)*V + v];
        bufA[v*2]   = x0; frag[r][0][0] = x0;
        bufA[v*2+1] = x1; frag[r][1][0] = x1;
    }
    __syncthreads();

    for (int w = 0; w < 4; ++w) {
#pragma unroll
        for (int kk = 0; kk < 8; ++kk) {
            if (w == 0 && kk == 0) continue;
            if (w == 3 && kk >= 1) break;
            const float* __restrict__ src = (kk & 1) ? bufA : bufB;
            float* __restrict__ dst       = (kk & 1) ? bufB : bufA;
#pragma unroll
            for (int r = 0; r < RPT; ++r) {
                int v = r*THREADS + t;
                float a00=0,a01=0,a10=0,a11=0,a20=0,a21=0,a30=0,a31=0;
                int e1 = e1r[r];
                for (int e = e0r[r]; e < e1; e += 4) {
                    const uint4 u = *(const uint4*)&ep[e];
                    float w0=__half2float(__ushort_as_half((unsigned short)(u.x>>16)));
                    float w1=__half2float(__ushort_as_half((unsigned short)(u.y>>16)));
                    float w2=__half2float(__ushort_as_half((unsigned short)(u.z>>16)));
                    float w3=__half2float(__ushort_as_half((unsigned short)(u.w>>16)));
                    const float2 g0 = *(const float2*)&src[(u.x&0xFFFFu)*2];
                    const float2 g1 = *(const float2*)&src[(u.y&0xFFFFu)*2];
                    const float2 g2 = *(const float2*)&src[(u.z&0xFFFFu)*2];
                    const float2 g3 = *(const float2*)&src[(u.w&0xFFFFu)*2];
                    a00 = fmaf(w0, g0.x, a00); a01 = fmaf(w0, g0.y, a01);
                    a10 = fmaf(w1, g1.x, a10); a11 = fmaf(w1, g1.y, a11);
                    a20 = fmaf(w2, g2.x, a20); a21 = fmaf(w2, g2.y, a21);
                    a30 = fmaf(w3, g3.x, a30); a31 = fmaf(w3, g3.y, a31);
                }
                float s0 = (a00+a10)+(a20+a30);
                float s1 = (a01+a11)+(a21+a31);
                float x0n, x1n;
                if (w == 0 && kk == 1) { x0n = s0; x1n = s1; }
                else { x0n = 2.f*s0 - dst[v*2]; x1n = 2.f*s1 - dst[v*2+1]; }
                dst[v*2]   = x0n;  frag[r][0][kk] = x0n;
                dst[v*2+1] = x1n;  frag[r][1][kk] = x1n;
            }
            __syncthreads();
        }
#pragma unroll
        for (int r = 0; r < RPT; ++r) {
            int v = r*THREADS + t;
#pragma unroll
            for (int j = 0; j < 2; ++j) {
                uint4 pk;
                pk.x = (unsigned)f2bf(frag[r][j][0]) | ((unsigned)f2bf(frag[r][j][1]) << 16);
                pk.y = (unsigned)f2bf(frag[r][j][2]) | ((unsigned)f2bf(frag[r][j][3]) << 16);
                pk.z = (unsigned)f2bf(frag[r][j][4]) | ((unsigned)f2bf(frag[r][j][5]) << 16);
                pk.w = (unsigned)f2bf(frag[r][j][6]) | ((unsigned)f2bf(frag[r][j][7]) << 16);
                *(uint4*)&stack[((size_t)(c0+j)*KP_ + w*8)*V + (size_t)v*8] = pk;
            }
        }
    }
}

// ---------- W prep: Wb[fin][g][f][kk] = bf16(W[f][fin*25 + g*8+kk]), 0-padded ----------
template<int FIN, int F>
__global__ __launch_bounds__(256) void k_wprep(const float* __restrict__ W,
                                               unsigned short* __restrict__ Wb) {
    int idx = blockIdx.x*256 + threadIdx.x;      // FIN*4*F*8
    int kk  = idx & 7;
    int f   = (idx >> 3) % F;
    int g   = (idx >> 3) / F % 4;
    int fin = idx / (8*F*4);
    int k = g*8 + kk;
    Wb[idx] = (k < K_) ? f2bf(W[(size_t)f*(FIN*K_) + fin*K_ + k]) : 0;
}

// ---------- layer-1 MFMA GEMM + relu + pool -> X0T2[(f*64+b)][v2] ----------
// grid (64 b, 32 vchunk); 4 waves, wave v-tile 32
__global__ __launch_bounds__(256) void k_gemm1(const unsigned short* __restrict__ stack,
                                               const unsigned short* __restrict__ Wb,
                                               const float* __restrict__ bias,
                                               float* __restrict__ X0T2) {
    __shared__ float Tsm[32][36];
    const int t = threadIdx.x, lane = t & 63, wave = t >> 6;
    const int b = blockIdx.x;
    const int v0 = blockIdx.y*128 + wave*32;
    const int m = lane & 15, g = lane >> 4;

    f32x4 acc[2][2];
#pragma unroll
    for (int mt = 0; mt < 2; ++mt)
#pragma unroll
        for (int ft = 0; ft < 2; ++ft) acc[mt][ft] = (f32x4){0.f,0.f,0.f,0.f};

#pragma unroll
    for (int fin = 0; fin < DF_; ++fin) {
        const size_t abase = ((size_t)((fin*64+b)*KP_ + g*8))*V1_ + (size_t)(v0+m)*8;
        const bf16x8 a0 = *(const bf16x8*)&stack[abase];
        const bf16x8 a1 = *(const bf16x8*)&stack[abase + 16*8];
        const bf16x8 w0 = *(const bf16x8*)&Wb[((fin*4+g)*F1_ + m)*8];
        const bf16x8 w1 = *(const bf16x8*)&Wb[((fin*4+g)*F1_ + 16 + m)*8];
        acc[0][0] = __builtin_amdgcn_mfma_f32_16x16x32_bf16(a0, w0, acc[0][0], 0,0,0);
        acc[0][1] = __builtin_amdgcn_mfma_f32_16x16x32_bf16(a0, w1, acc[0][1], 0,0,0);
        acc[1][0] = __builtin_amdgcn_mfma_f32_16x16x32_bf16(a1, w0, acc[1][0], 0,0,0);
        acc[1][1] = __builtin_amdgcn_mfma_f32_16x16x32_bf16(a1, w1, acc[1][1], 0,0,0);
    }
    float bv[2] = { bias[m], bias[16+m] };
#pragma unroll
    for (int mt = 0; mt < 2; ++mt)
#pragma unroll
        for (int ft = 0; ft < 2; ++ft) {
            f32x4 a = acc[mt][ft];
            float mx = fmaxf(fmaxf(a[0],a[1]), fmaxf(a[2],a[3])) + bv[ft];
            Tsm[ft*16 + m][wave*8 + mt*4 + g] = fmaxf(mx, 0.f);
        }
    __syncthreads();
    const int f = t >> 3, vg = t & 7;
    float4 o = *(const float4*)&Tsm[f][vg*4];
    *(float4*)&X0T2[(size_t)(f*64+b)*V2_ + blockIdx.y*32 + vg*4] = o;
}

// ---------- layer-2 MFMA GEMM + relu + pool -> FCINT[v2*64+f][b] ----------
// grid (64 b, 8 vchunk); 4 waves, wave v-tile 32
__global__ __launch_bounds__(256) void k_gemm2(const unsigned short* __restrict__ stack,
                                               const unsigned short* __restrict__ Wb,
                                               const float* __restrict__ bias,
                                               float* __restrict__ FCINT) {
    const int t = threadIdx.x, lane = t & 63, wave = t >> 6;
    const int b = blockIdx.x;
    const int v0 = blockIdx.y*128 + wave*32;
    const int m = lane & 15, g = lane >> 4;

    f32x4 acc[2][4];
#pragma unroll
    for (int mt = 0; mt < 2; ++mt)
#pragma unroll
        for (int ft = 0; ft < 4; ++ft) acc[mt][ft] = (f32x4){0.f,0.f,0.f,0.f};

#pragma unroll 4
    for (int fin = 0; fin < F1_; ++fin) {
        const size_t abase = ((size_t)((fin*64+b)*KP_ + g*8))*V2_ + (size_t)(v0+m)*8;
        const bf16x8 a0 = *(const bf16x8*)&stack[abase];
        const bf16x8 a1 = *(const bf16x8*)&stack[abase + 16*8];
#pragma unroll
        for (int ft = 0; ft < 4; ++ft) {
            const bf16x8 bw = *(const bf16x8*)&Wb[((fin*4+g)*F2_ + ft*16 + m)*8];
            acc[0][ft] = __builtin_amdgcn_mfma_f32_16x16x32_bf16(a0, bw, acc[0][ft], 0,0,0);
            acc[1][ft] = __builtin_amdgcn_mfma_f32_16x16x32_bf16(a1, bw, acc[1][ft], 0,0,0);
        }
    }
#pragma unroll
    for (int mt = 0; mt < 2; ++mt)
#pragma unroll
        for (int ft = 0; ft < 4; ++ft) {
            f32x4 a = acc[mt][ft];
            float mx = fmaxf(fmaxf(a[0],a[1]), fmaxf(a[2],a[3])) + bias[ft*16 + m];
            mx = fmaxf(mx, 0.f);
            int v2 = blockIdx.y*32 + wave*8 + mt*4 + g;
            FCINT[((size_t)v2*64 + ft*16 + m)*64 + b] = mx;
        }
}

// ---------- FC1: O[b][j] (+= atomics over i-splits), AT layout [i][b] ----------
__global__ __launch_bounds__(256) void k_fc1_init(const float* __restrict__ bias,
                                                  float* __restrict__ O) {
    int idx = blockIdx.x*256 + threadIdx.x;
    O[idx] = bias[idx & (FC1F_-1)];
}

__global__ __launch_bounds__(256) void k_fc1(const float* __restrict__ AT,
                                             const float* __restrict__ W,
                                             float* __restrict__ O) {
    const int t = threadIdx.x;
    const int b = t & 63;
    const int jq = __builtin_amdgcn_readfirstlane(t >> 6);
    const int j0 = blockIdx.x*32 + jq*8;
    const int i0 = blockIdx.y*1024;
    float acc[8] = {};
    for (int i = i0; i < i0 + 1024; i += 4) {
        float a0 = AT[(size_t)(i+0)*64 + b];
        float a1 = AT[(size_t)(i+1)*64 + b];
        float a2 = AT[(size_t)(i+2)*64 + b];
        float a3 = AT[(size_t)(i+3)*64 + b];
#pragma unroll
        for (int jj = 0; jj < 8; ++jj) {
            const float* wp = &W[(size_t)(j0+jj)*FCIN_ + i];
            acc[jj] = fmaf(a0, wp[0], acc[jj]);
            acc[jj] = fmaf(a1, wp[1], acc[jj]);
            acc[jj] = fmaf(a2, wp[2], acc[jj]);
            acc[jj] = fmaf(a3, wp[3], acc[jj]);
        }
    }
#pragma unroll
    for (int jj = 0; jj < 8; ++jj)
        atomicAdd(&O[b*FC1F_ + j0 + jj], acc[jj]);
}

// ---------- FC2 (relu on FC1 output applied here) ----------
__global__ void k_fc2(const float* __restrict__ O1, const float* __restrict__ W2,
                      const float* __restrict__ b2, float* __restrict__ out) {
    int c = blockIdx.x;
    int b = threadIdx.x;
    float s = b2[c];
    for (int j = 0; j < FC1F_; ++j)
        s = fmaf(fmaxf(O1[b*FC1F_ + j], 0.f), W2[c*FC1F_ + j], s);
    out[b*FC2F_ + c] = s;
}

extern "C" void kernel_launch(void* const* d_in, const int* in_sizes, int n_in,
                              void* d_out, int out_size, void* d_ws, size_t ws_size,
                              hipStream_t stream) {
    const float* x   = (const float*)d_in[0];
    const int*   l1r = (const int*)d_in[1];
    const int*   l1c = (const int*)d_in[2];
    const float* l1v = (const float*)d_in[3];
    const int*   l2r = (const int*)d_in[4];
    const int*   l2c = (const int*)d_in[5];
    const float* l2v = (const float*)d_in[6];
    const float* w1  = (const float*)d_in[7];
    const float* b1  = (const float*)d_in[8];
    const float* w2  = (const float*)d_in[9];
    const float* b2  = (const float*)d_in[10];
    const float* fw1 = (const float*)d_in[11];
    const float* fb1 = (const float*)d_in[12];
    const float* fw2 = (const float*)d_in[13];
    const float* fb2 = (const float*)d_in[14];
    float* out = (float*)d_out;

    char* wsp = (char*)d_ws;
    size_t off = 0;
    auto alloc = [&](size_t bytes) -> void* {
        void* p = wsp + off;
        off += (bytes + 255) & ~size_t(255);
        return p;
    };
    float*          X0T1  = (float*)alloc((size_t)C1_*V1_*4);
    unsigned short* STACK = (unsigned short*)alloc((size_t)C1_*V1_*KP_*2);  // reused by layer 2
    float*          X0T2  = (float*)alloc((size_t)C2_*V2_*4);
    float*          FCINT = (float*)alloc((size_t)FCIN_*B_*4);
    float*          FC1O  = (float*)alloc((size_t)B_*FC1F_*4);
    unsigned short* WB1   = (unsigned short*)alloc((size_t)DF_*4*F1_*8*2);
    unsigned short* WB2   = (unsigned short*)alloc((size_t)F1_*4*F2_*8*2);
    int*      cnt1  = (int*)alloc(V1_*4);
    int*      offs1 = (int*)alloc((V1_+1)*4);
    int*      cur1  = (int*)alloc(V1_*4);
    unsigned* ep1   = (unsigned*)alloc((size_t)(E1_ + 4*V1_)*4);
    int*      cnt2  = (int*)alloc(V2_*4);
    int*      offs2 = (int*)alloc((V2_+1)*4);
    int*      cur2  = (int*)alloc(V2_*4);
    unsigned* ep2   = (unsigned*)alloc((size_t)(E2_ + 4*V2_)*4);

    // --- CSR build both layers + W prep ---
    hipMemsetAsync(cnt1, 0, V1_*4, stream);
    hipMemsetAsync(ep1, 0, (size_t)(E1_ + 4*V1_)*4, stream);
    hipMemsetAsync(cnt2, 0, V2_*4, stream);
    hipMemsetAsync(ep2, 0, (size_t)(E2_ + 4*V2_)*4, stream);
    hipLaunchKernelGGL(k_count,   dim3(E1_/256), dim3(256), 0, stream, l1r, E1_, cnt1);
    hipLaunchKernelGGL(k_scan,    dim3(1),       dim3(256), 0, stream, cnt1, V1_, offs1, cur1);
    hipLaunchKernelGGL(k_scatter, dim3(E1_/256), dim3(256), 0, stream, l1r, l1c, l1v, E1_, cur1, ep1);
    hipLaunchKernelGGL(k_count,   dim3(E2_/256), dim3(256), 0, stream, l2r, E2_, cnt2);
    hipLaunchKernelGGL(k_scan,    dim3(1),       dim3(256), 0, stream, cnt2, V2_, offs2, cur2);
    hipLaunchKernelGGL(k_scatter, dim3(E2_/256), dim3(256), 0, stream, l2r, l2c, l2v, E2_, cur2, ep2);
    hipLaunchKernelGGL((k_wprep<DF_,F1_>),  dim3(DF_*4*F1_*8/256),  dim3(256), 0, stream, w1, WB1);
    hipLaunchKernelGGL((k_wprep<F1_,F2_>),  dim3(F1_*4*F2_*8/256),  dim3(256), 0, stream, w2, WB2);

    // --- layer 1 ---
    hipLaunchKernelGGL(k_transpose_x, dim3(V1_/16), dim3(256), 0, stream, x, X0T1);
    hipLaunchKernelGGL((k_cheb<V1_,1024>), dim3(C1_/2), dim3(1024), 0, stream,
                       X0T1, offs1, ep1, STACK);
    hipLaunchKernelGGL(k_gemm1, dim3(64, 32), dim3(256), 0, stream, STACK, WB1, b1, X0T2);

    // --- layer 2 ---
    hipLaunchKernelGGL((k_cheb<V2_,256>), dim3(C2_/2), dim3(256), 0, stream,
                       X0T2, offs2, ep2, STACK);
    hipLaunchKernelGGL(k_gemm2, dim3(64, 8), dim3(256), 0, stream, STACK, WB2, b2, FCINT);

    // --- FC ---
    hipLaunchKernelGGL(k_fc1_init, dim3(B_*FC1F_/256), dim3(256), 0, stream, fb1, FC1O);
    hipLaunchKernelGGL(k_fc1, dim3(16, 16), dim3(256), 0, stream, FCINT, fw1, FC1O);
    hipLaunchKernelGGL(k_fc2, dim3(FC2F_), dim3(B_), 0, stream, FC1O, fw2, fb2, out);
}